// Round 3
// baseline (244.743 us; speedup 1.0000x reference)
//
#include <hip/hip_runtime.h>
#include <math.h>

#define B    128
#define CTRL 1024
#define NN   4096
#define MM   64
#define OD   70     // M + 6
#define NC   8      // n-chunks per batch
#define CHUNK 512   // NN / NC
#define SCW  80     // scalars row stride: [0..63]=k, 64=knorm, 65=beta,
                    // 66=g, 67..69=s0..s2, 70=gamma

// DPP-based 16-lane group sum (pure VALU, no LDS pipe).
#define DPP_ADD(v, ctrl)                                                        \
    do {                                                                        \
        int _t = __builtin_amdgcn_update_dpp(0, __float_as_int(v), (ctrl),      \
                                             0xF, 0xF, true);                   \
        (v) += __int_as_float(_t);                                              \
    } while (0)

__device__ inline float sum16(float v) {
    DPP_ADD(v, 0xB1);    // quad_perm xor1
    DPP_ADD(v, 0x4E);    // quad_perm xor2
    DPP_ADD(v, 0x141);   // row_half_mirror
    DPP_ADD(v, 0x140);   // row_mirror
    return v;
}

// ---------------- kernel 1: all control scalars, one block per batch --------
// 70 dots of length 1024 + derived scalars -> sc[b][SCW]. ~2 us total.
__global__ void k_ctrl(const float* __restrict__ emb,
                       const float* __restrict__ fc_w,
                       const float* __restrict__ fc_b,
                       float* __restrict__ sc) {
    const int b = blockIdx.x;
    const int t = threadIdx.x;
    __shared__ float o_sh[OD];

    {
        const int w = t >> 6, l = t & 63;
        const float4* e4 = (const float4*)(emb + (size_t)b * CTRL);
        float4 e0 = e4[l], e1 = e4[l + 64], e2 = e4[l + 128], e3 = e4[l + 192];
        for (int j = w; j < OD; j += 4) {
            const float4* w4 = (const float4*)(fc_w + (size_t)j * CTRL);
            float4 w0 = w4[l], w1 = w4[l + 64], w2 = w4[l + 128], w3 = w4[l + 192];
            float s = e0.x * w0.x + e0.y * w0.y + e0.z * w0.z + e0.w * w0.w;
            s += e1.x * w1.x + e1.y * w1.y + e1.z * w1.z + e1.w * w1.w;
            s += e2.x * w2.x + e2.y * w2.y + e2.z * w2.z + e2.w * w2.w;
            s += e3.x * w3.x + e3.y * w3.y + e3.z * w3.z + e3.w * w3.w;
            for (int off = 32; off; off >>= 1) s += __shfl_xor(s, off);
            if (l == 0) o_sh[j] = s + fc_b[j];
        }
    }
    __syncthreads();

    float* sb = sc + (size_t)b * SCW;
    if (t < MM) {                      // k + knorm
        float kv = o_sh[t];
        sb[t] = kv;
        float ss = kv * kv;
        for (int off = 32; off; off >>= 1) ss += __shfl_xor(ss, off);
        if (t == 0) sb[MM] = sqrtf(ss);
    } else if (t == MM) {              // tail scalars, serial (6 values)
        float x = o_sh[MM];
        sb[MM + 1] = fmaxf(x, 0.f) + log1pf(expf(-fabsf(x)));      // beta
        sb[MM + 2] = 1.f / (1.f + __expf(-o_sh[MM + 1]));          // g
        float a0 = o_sh[MM + 2], a1 = o_sh[MM + 3], a2 = o_sh[MM + 4];
        float mx = fmaxf(a0, fmaxf(a1, a2));
        float e0 = __expf(a0 - mx), e1 = __expf(a1 - mx), e2 = __expf(a2 - mx);
        float es = e0 + e1 + e2;
        sb[MM + 3] = e0 / es; sb[MM + 4] = e1 / es; sb[MM + 5] = e2 / es;
        float xg = o_sh[MM + 5];
        sb[MM + 6] = 1.f + fmaxf(xg, 0.f) + log1pf(__expf(-fabsf(xg)));  // gamma
    }
}

// ---------------- kernel 2: HBM pass over mem: ev = exp(beta*cos_sim) ------
// grid (NC, B), block 256. Minimal head (~3 loads) then pure stream.
__global__ void k_sim(const float* __restrict__ mem,
                      const float* __restrict__ sc,
                      float* __restrict__ evb,
                      float* __restrict__ zpart) {
    const int c = blockIdx.x;
    const int b = blockIdx.y;
    const int t = threadIdx.x;
    const int n0 = c * CHUNK;
    const size_t boff = (size_t)b * NN;

    __shared__ __align__(16) float ev_sh[CHUNK];
    __shared__ float red[4];

    const float* sb = sc + (size_t)b * SCW;
    const int lane16 = t & 15;
    const int rgrp   = t >> 4;
    const float4 k4 = ((const float4*)sb)[lane16];
    const float knorm = sb[MM];
    const float beta  = sb[MM + 1];

    float evsum = 0.f;
    #pragma unroll 8
    for (int i = 0; i < 32; ++i) {
        int row = rgrp + i * 16;
        const float4* m4 = (const float4*)(mem + (boff + n0 + row) * MM);
        float4 v = m4[lane16];
        float dot = v.x * k4.x + v.y * k4.y + v.z * k4.z + v.w * k4.w;
        float ssq = v.x * v.x + v.y * v.y + v.z * v.z + v.w * v.w;
        dot = sum16(dot);
        ssq = sum16(ssq);
        if (lane16 == 0) {
            // |beta*sim| <= ~6, exp fp32-safe; softmax shift-invariant
            float e = __expf(beta * dot / (knorm * sqrtf(ssq) + 1e-16f));
            ev_sh[row] = e;
            evsum += e;
        }
    }
    for (int off = 32; off; off >>= 1) evsum += __shfl_xor(evsum, off);
    if ((t & 63) == 0) red[t >> 6] = evsum;
    __syncthreads();
    if (t == 0) zpart[b * NC + c] = red[0] + red[1] + red[2] + red[3];
    ((float2*)(evb + boff + n0))[t] = ((const float2*)ev_sh)[t];
}

// ---------------- kernel 3: wg -> wt -> wp (cheap, 4 MB), ppart, zero r ----
__global__ void k_wp(const float* __restrict__ w_prev,
                     const float* __restrict__ sc,
                     const float* __restrict__ evb,
                     const float* __restrict__ zpart,
                     float* __restrict__ wpb,
                     float* __restrict__ ppart,
                     float* __restrict__ r_out) {
    const int c = blockIdx.x;
    const int b = blockIdx.y;
    const int t = threadIdx.x;
    const int n0 = c * CHUNK;
    const size_t boff = (size_t)b * NN;

    __shared__ float wg_sh[CHUNK + 2];
    __shared__ float red[4];

    if (c == 0 && t < MM) r_out[(size_t)b * MM + t] = 0.f;

    const float* sb = sc + (size_t)b * SCW;
    const float g  = sb[MM + 2];
    const float s0 = sb[MM + 3], s1 = sb[MM + 4], s2 = sb[MM + 5];
    const float gamma = sb[MM + 6];

    float zsum = 0.f;
    #pragma unroll
    for (int i = 0; i < NC; ++i) zsum += zpart[b * NC + i];
    const float invsum = 1.f / zsum;

    for (int idx = t; idx < CHUNK + 2; idx += 256) {
        int n = (n0 - 1 + idx) & (NN - 1);
        wg_sh[idx] = g * evb[boff + n] * invsum + (1.f - g) * w_prev[boff + n];
    }
    __syncthreads();

    float wt0 = s0 * wg_sh[t]       + s1 * wg_sh[t + 1]   + s2 * wg_sh[t + 2];
    float wt1 = s0 * wg_sh[t + 256] + s1 * wg_sh[t + 257] + s2 * wg_sh[t + 258];
    float wp0 = __powf(wt0, gamma);
    float wp1 = __powf(wt1, gamma);
    wpb[boff + n0 + t]       = wp0;
    wpb[boff + n0 + t + 256] = wp1;

    float ps = wp0 + wp1;
    for (int off = 32; off; off >>= 1) ps += __shfl_xor(ps, off);
    if ((t & 63) == 0) red[t >> 6] = ps;
    __syncthreads();
    if (t == 0) ppart[b * NC + c] = red[0] + red[1] + red[2] + red[3];
}

// ---------------- kernel 4: L3 pass over mem + normalize w and r ------------
// psum known here -> w_out written final; r partials pre-scaled by invz and
// atomically accumulated (r_out zeroed by k_wp).
__global__ void k_final(const float* __restrict__ mem,
                        const float* __restrict__ wpb,
                        const float* __restrict__ ppart,
                        float* __restrict__ r_out,
                        float* __restrict__ w_out) {
    const int c = blockIdx.x;
    const int b = blockIdx.y;
    const int t = threadIdx.x;
    const int n0 = c * CHUNK;
    const size_t boff = (size_t)b * NN;

    __shared__ float wp_sh[CHUNK];
    __shared__ __align__(16) float4 acc_sh[256];

    float ps = 0.f;
    #pragma unroll
    for (int i = 0; i < NC; ++i) ps += ppart[b * NC + i];
    const float invz = 1.f / (ps + 1e-16f);

    float2 wv2 = ((const float2*)(wpb + boff + n0))[t];
    ((float2*)(wp_sh))[t] = wv2;
    ((float2*)(w_out + boff + n0))[t] = make_float2(wv2.x * invz, wv2.y * invz);
    __syncthreads();

    const int m4i = t & 15;
    const int rg  = t >> 4;
    float4 acc = {0.f, 0.f, 0.f, 0.f};
    const float4* base = (const float4*)(mem + (boff + n0) * MM);
    #pragma unroll 8
    for (int i = 0; i < 32; ++i) {
        int row = rg + i * 16;
        float4 v = base[(size_t)row * 16 + m4i];
        float wv = wp_sh[row];
        acc.x += wv * v.x; acc.y += wv * v.y;
        acc.z += wv * v.z; acc.w += wv * v.w;
    }
    acc_sh[t] = acc;
    __syncthreads();
    if (t < 16) {
        float4 s = {0.f, 0.f, 0.f, 0.f};
        for (int j = 0; j < 16; ++j) {
            float4 v = acc_sh[t + j * 16];
            s.x += v.x; s.y += v.y; s.z += v.z; s.w += v.w;
        }
        float* rb = r_out + (size_t)b * MM + t * 4;
        atomicAdd(rb + 0, s.x * invz);
        atomicAdd(rb + 1, s.y * invz);
        atomicAdd(rb + 2, s.z * invz);
        atomicAdd(rb + 3, s.w * invz);
    }
}

// ---------------------------------------------------------------------------
extern "C" void kernel_launch(void* const* d_in, const int* in_sizes, int n_in,
                              void* d_out, int out_size, void* d_ws, size_t ws_size,
                              hipStream_t stream) {
    const float* emb    = (const float*)d_in[0];   // B x CTRL
    const float* w_prev = (const float*)d_in[1];   // B x N
    const float* mem    = (const float*)d_in[2];   // B x N x M
    const float* fc_w   = (const float*)d_in[3];   // OD x CTRL
    const float* fc_b   = (const float*)d_in[4];   // OD

    float* r_out = (float*)d_out;                  // B x M
    float* w_out = r_out + (size_t)B * MM;         // B x N

    // workspace layout (fp32)
    float* evb   = (float*)d_ws;                   // B x N
    float* wpb   = evb + (size_t)B * NN;           // B x N
    float* sc    = wpb + (size_t)B * NN;           // B x SCW
    float* zpart = sc + (size_t)B * SCW;           // B x NC
    float* ppart = zpart + (size_t)B * NC;         // B x NC

    k_ctrl <<<dim3(B), 256, 0, stream>>>(emb, fc_w, fc_b, sc);
    k_sim  <<<dim3(NC, B), 256, 0, stream>>>(mem, sc, evb, zpart);
    k_wp   <<<dim3(NC, B), 256, 0, stream>>>(w_prev, sc, evb, zpart, wpb, ppart, r_out);
    k_final<<<dim3(NC, B), 256, 0, stream>>>(mem, wpb, ppart, r_out, w_out);
}

// Round 4
// 231.433 us; speedup vs baseline: 1.0575x; 1.0575x over previous
//
#include <hip/hip_runtime.h>
#include <math.h>

#define B    128
#define CTRL 1024
#define NN   4096
#define MM   64
#define OD   70     // M + 6
#define NC   8      // n-chunks per batch
#define CHUNK 512   // NN / NC

// DPP-based 16-lane group sum (pure VALU, no LDS pipe).
#define DPP_ADD(v, ctrl)                                                        \
    do {                                                                        \
        int _t = __builtin_amdgcn_update_dpp(0, __float_as_int(v), (ctrl),      \
                                             0xF, 0xF, true);                   \
        (v) += __int_as_float(_t);                                              \
    } while (0)

__device__ inline float sum16(float v) {
    DPP_ADD(v, 0xB1);    // quad_perm xor1
    DPP_ADD(v, 0x4E);    // quad_perm xor2
    DPP_ADD(v, 0x141);   // row_half_mirror
    DPP_ADD(v, 0x140);   // row_mirror
    return v;
}

// ---------------- kernel 1: o = emb @ fc_w.T + fc_b ; zero accumulators -----
// One wave per dot: 64 lanes x 4 float4 = 1024 floats. No LDS, no barriers.
// grid (ceil(OD/4)=18, B), block 256 (4 waves = 4 dots per block).
__global__ void k_ctrl(const float* __restrict__ emb,
                       const float* __restrict__ fc_w,
                       const float* __restrict__ fc_b,
                       float* __restrict__ o,
                       float* __restrict__ zsum,
                       float* __restrict__ psum,
                       float* __restrict__ rnum) {
    const int b = blockIdx.y;
    const int t = threadIdx.x;
    const int j = blockIdx.x * 4 + (t >> 6);
    const int l = t & 63;

    if (blockIdx.x == 0) {
        if (t < MM) rnum[(size_t)b * MM + t] = 0.f;
        else if (t == MM) { zsum[b] = 0.f; psum[b] = 0.f; }
    }

    if (j < OD) {
        const float4* e4 = (const float4*)(emb + (size_t)b * CTRL);
        const float4* w4 = (const float4*)(fc_w + (size_t)j * CTRL);
        float4 e0 = e4[l], e1 = e4[l + 64], e2 = e4[l + 128], e3 = e4[l + 192];
        float4 w0 = w4[l], w1 = w4[l + 64], w2 = w4[l + 128], w3 = w4[l + 192];
        float s = e0.x * w0.x + e0.y * w0.y + e0.z * w0.z + e0.w * w0.w;
        s += e1.x * w1.x + e1.y * w1.y + e1.z * w1.z + e1.w * w1.w;
        s += e2.x * w2.x + e2.y * w2.y + e2.z * w2.z + e2.w * w2.w;
        s += e3.x * w3.x + e3.y * w3.y + e3.z * w3.z + e3.w * w3.w;
        for (int off = 32; off; off >>= 1) s += __shfl_xor(s, off);
        if (l == 0) o[(size_t)b * OD + j] = s + fc_b[j];
    }
}

// ---------------- kernel 2: ev[b,n] = exp(beta*cos_sim) ; zsum[b] += ... ----
// grid (NC, B), block 256. 16 lanes per row; 512 rows per block.
__global__ void k_sim(const float* __restrict__ mem,
                      const float* __restrict__ o,
                      float* __restrict__ ev_buf,
                      float* __restrict__ zsum) {
    int b  = blockIdx.y;
    int n0 = blockIdx.x * CHUNK;
    int t  = threadIdx.x;

    __shared__ __align__(16) float k_sh[MM];
    __shared__ float kb[2];   // knorm, beta
    __shared__ float red[4];

    if (t < MM) {                           // wave 0: knorm via shuffle reduce
        float kv = o[(size_t)b * OD + t];
        k_sh[t] = kv;
        float ss = kv * kv;
        for (int off = 32; off; off >>= 1) ss += __shfl_xor(ss, off);
        if (t == 0) kb[0] = sqrtf(ss);
    } else if (t == MM) {                   // wave 1 lane 0: beta = softplus
        float x = o[(size_t)b * OD + MM];
        kb[1] = fmaxf(x, 0.f) + log1pf(expf(-fabsf(x)));
    }
    __syncthreads();
    float knorm = kb[0], beta = kb[1];

    int lane16 = t & 15;
    int rgrp   = t >> 4;
    float4 k4 = ((const float4*)k_sh)[lane16];

    float evsum = 0.f;
    #pragma unroll 8
    for (int i = 0; i < 32; ++i) {
        int n = n0 + rgrp + i * 16;
        const float4* m4 = (const float4*)(mem + ((size_t)b * NN + n) * MM);
        float4 v = m4[lane16];
        float dot = v.x * k4.x + v.y * k4.y + v.z * k4.z + v.w * k4.w;
        float ssq = v.x * v.x + v.y * v.y + v.z * v.z + v.w * v.w;
        dot = sum16(dot);
        ssq = sum16(ssq);
        if (lane16 == 0) {
            // no max-shift: |beta*sim| <= ~5, exp fp32-safe; softmax shift-invariant
            float e = __expf(beta * dot / (knorm * sqrtf(ssq) + 1e-16f));
            ev_buf[(size_t)b * NN + n] = e;
            evsum += e;
        }
    }
    for (int off = 32; off; off >>= 1) evsum += __shfl_xor(evsum, off);
    if ((t & 63) == 0) red[t >> 6] = evsum;
    __syncthreads();
    if (t == 0) atomicAdd(&zsum[b], red[0] + red[1] + red[2] + red[3]);
}

// ---------------- kernel 3: wp = wt^gamma (LDS) ; psum += ; rnum += sweep ---
// grid (NC, B), block 256. powf overlaps the L3-served second memory sweep.
__global__ void k_wr(const float* __restrict__ mem,
                     const float* __restrict__ w_prev,
                     const float* __restrict__ o,
                     const float* __restrict__ ev_buf,
                     const float* __restrict__ zsum,
                     float* __restrict__ wp_buf,
                     float* __restrict__ psum,
                     float* __restrict__ rnum) {
    int c = blockIdx.x;
    int b = blockIdx.y;
    int t = threadIdx.x;
    int n0 = c * CHUNK;

    __shared__ float wg_sh[CHUNK + 2];
    __shared__ float wp_sh[CHUNK];
    __shared__ __align__(16) float4 acc_sh[256];
    __shared__ float red[4];

    // scalars (every thread, broadcast loads)
    const float* ob = o + (size_t)b * OD;
    float g  = 1.f / (1.f + __expf(-ob[MM + 1]));
    float a0 = ob[MM + 2], a1 = ob[MM + 3], a2 = ob[MM + 4];
    float mx = fmaxf(a0, fmaxf(a1, a2));
    float e0 = __expf(a0 - mx), e1 = __expf(a1 - mx), e2 = __expf(a2 - mx);
    float es = e0 + e1 + e2;
    float s0 = e0 / es, s1 = e1 / es, s2 = e2 / es;
    float xg = ob[MM + 5];
    float gamma = 1.f + fmaxf(xg, 0.f) + log1pf(__expf(-fabsf(xg)));
    float invsum = 1.f / zsum[b];

    size_t boff = (size_t)b * NN;
    for (int idx = t; idx < CHUNK + 2; idx += 256) {
        int n = (n0 - 1 + idx) & (NN - 1);
        wg_sh[idx] = g * ev_buf[boff + n] * invsum + (1.f - g) * w_prev[boff + n];
    }
    __syncthreads();

    float wt0 = s0 * wg_sh[t]       + s1 * wg_sh[t + 1]   + s2 * wg_sh[t + 2];
    float wt1 = s0 * wg_sh[t + 256] + s1 * wg_sh[t + 257] + s2 * wg_sh[t + 258];
    float wp0 = __powf(wt0, gamma);
    float wp1 = __powf(wt1, gamma);
    wp_sh[t]       = wp0;
    wp_sh[t + 256] = wp1;
    wp_buf[boff + n0 + t]       = wp0;
    wp_buf[boff + n0 + t + 256] = wp1;

    float ps = wp0 + wp1;
    for (int off = 32; off; off >>= 1) ps += __shfl_xor(ps, off);
    if ((t & 63) == 0) red[t >> 6] = ps;
    __syncthreads();
    if (t == 0) atomicAdd(&psum[b], red[0] + red[1] + red[2] + red[3]);

    // ---- sweep 2: rnum[b,:] += sum_n wp[n] * mem[b,n,:] (L3-resident) ----
    int m4 = t & 15;
    int rg = t >> 4;
    float4 acc = {0.f, 0.f, 0.f, 0.f};
    const float4* base = (const float4*)(mem + (boff + n0) * MM);
    #pragma unroll 8
    for (int i = 0; i < 32; ++i) {
        int row = rg + i * 16;
        float4 v = base[(size_t)row * 16 + m4];
        float wv = wp_sh[row];
        acc.x += wv * v.x; acc.y += wv * v.y;
        acc.z += wv * v.z; acc.w += wv * v.w;
    }
    acc_sh[t] = acc;
    __syncthreads();
    if (t < 16) {
        float4 s = {0.f, 0.f, 0.f, 0.f};
        for (int j = 0; j < 16; ++j) {
            float4 v = acc_sh[t + j * 16];
            s.x += v.x; s.y += v.y; s.z += v.z; s.w += v.w;
        }
        float* rb = rnum + (size_t)b * MM + t * 4;
        atomicAdd(rb + 0, s.x);
        atomicAdd(rb + 1, s.y);
        atomicAdd(rb + 2, s.z);
        atomicAdd(rb + 3, s.w);
    }
}

// ---------------- kernel 4: normalize w and r by psum+eps -------------------
__global__ void k_norm(const float* __restrict__ wp_buf,
                       const float* __restrict__ psum,
                       const float* __restrict__ rnum,
                       float* __restrict__ r_out,
                       float* __restrict__ w_out) {
    int c = blockIdx.x;
    int b = blockIdx.y;
    int t = threadIdx.x;
    float invz = 1.f / (psum[b] + 1e-16f);
    size_t boff = (size_t)b * NN + (size_t)c * CHUNK;
    w_out[boff + t]       = wp_buf[boff + t] * invz;
    w_out[boff + t + 256] = wp_buf[boff + t + 256] * invz;
    if (c == 0 && t < MM)
        r_out[(size_t)b * MM + t] = rnum[(size_t)b * MM + t] * invz;
}

// ---------------------------------------------------------------------------
extern "C" void kernel_launch(void* const* d_in, const int* in_sizes, int n_in,
                              void* d_out, int out_size, void* d_ws, size_t ws_size,
                              hipStream_t stream) {
    const float* emb    = (const float*)d_in[0];   // B x CTRL
    const float* w_prev = (const float*)d_in[1];   // B x N
    const float* mem    = (const float*)d_in[2];   // B x N x M
    const float* fc_w   = (const float*)d_in[3];   // OD x CTRL
    const float* fc_b   = (const float*)d_in[4];   // OD

    float* r_out = (float*)d_out;                  // B x M
    float* w_out = r_out + (size_t)B * MM;         // B x N

    // workspace layout (fp32)
    float* ev   = (float*)d_ws;                    // B x N
    float* wp   = ev + (size_t)B * NN;             // B x N
    float* o    = wp + (size_t)B * NN;             // B x OD
    float* zsum = o + (size_t)B * OD;              // B
    float* psum = zsum + B;                        // B
    float* rnum = psum + B;                        // B x M

    k_ctrl<<<dim3((OD + 3) / 4, B), 256, 0, stream>>>(emb, fc_w, fc_b, o, zsum, psum, rnum);
    k_sim <<<dim3(NC, B), 256, 0, stream>>>(mem, o, ev, zsum);
    k_wr  <<<dim3(NC, B), 256, 0, stream>>>(mem, w_prev, o, ev, zsum, wp, psum, rnum);
    k_norm<<<dim3(NC, B), 256, 0, stream>>>(wp, psum, rnum, r_out, w_out);
}